// Round 15
// baseline (49.572 us; speedup 1.0000x reference)
//
#include <hip/hip_runtime.h>
#include <math.h>

// Lee Oscillator: per-element 100-step chaotic recurrence, time-max-pooled.
// Bitwise-matches jax/XLA-CPU f32 semantics (PROVEN: rounds 6-14 absmax=0.0).
// The arithmetic (xla_tanhf/xla_expf/div_exact/fusion pattern) must not change.
//
// Round-15: revert to R13's 1-elem/lane k_process (R12/R13/R14 proved wave/ILP
// knobs all land at the same ~55% duty). New lever: EXACT period-2 early exit.
// t=1 dynamics reduce to w'=tanh(25w+5s)-tanh(5w); for |s|>~0.12 the orbit
// contracts onto a period-2 cycle (2-step factor 0.07-0.5) and becomes
// bitwise-periodic in 15-60 steps. state_t==state_{t-2} (bit compare) =>
// all future states replay, Dmax frozen => break. EXACT, zero risk.
// Worklist split: core (|sim0|<=0.13, chaotic, no check) at wl front;
// edge (0.13<|sim0|<=0.21, checked) at wl back -> waves are band-homogeneous
// so __all(periodic) actually fires.

#define N_STEPS 100

typedef float v2f __attribute__((ext_vector_type(2)));
__device__ __forceinline__ v2f splat2(float s){ v2f v; v.x = s; v.y = s; return v; }

// (a1,a2,a3,a4,b1,b2,b3,b4,xi_E,xi_I,mu,e,k) for oscillator types 1..8 (f32)
__constant__ float PAR[8][13] = {
    { 0.0f,  5.0f,  5.0f,  1.0f,  0.0f, -1.0f,  1.0f,  0.0f, 0.0f, 0.0f, 5.0f, 0.001f, 500.0f},
    { 0.5f,  0.55f, 0.55f, -0.5f,  0.5f, -0.55f, -0.55f, -0.5f, 0.0f, 0.0f, 1.0f, 0.001f, 50.0f},
    { 0.5f,  0.6f,  0.55f,  0.5f, -0.5f, -0.6f,  -0.55f,  0.5f, 0.0f, 0.0f, 1.0f, 0.001f, 50.0f},
    {-0.5f,  0.55f, 0.55f, -0.5f, -0.5f, -0.55f, -0.55f,  0.5f, 0.0f, 0.0f, 1.0f, 0.001f, 50.0f},
    {-0.9f,  0.9f,  0.9f,  -0.9f,  0.9f, -0.9f,  -0.9f,   0.9f, 0.0f, 0.0f, 1.0f, 0.001f, 50.0f},
    {-0.9f,  0.9f,  0.9f,  -0.9f,  0.9f, -0.9f,  -0.9f,   0.9f, 0.0f, 0.0f, 1.0f, 0.001f, 300.0f},
    {-5.0f,  5.0f,  5.0f,  -5.0f,  1.0f, -1.0f,  -1.0f,   1.0f, 0.0f, 0.0f, 1.0f, 0.001f, 50.0f},
    {-5.0f,  5.0f,  5.0f,  -5.0f,  1.0f, -1.0f,  -1.0f,   1.0f, 0.0f, 0.0f, 1.0f, 0.001f, 300.0f},
};

// XLA CPU f32 tanh — scalar form with IEEE '/'. Used OUTSIDE the hot loop.
// [bitwise-verified rounds 6-14]
__device__ __forceinline__ float xla_tanhf(float x) {
#pragma clang fp contract(off)
    float ax = fabsf(x);
    float xc = fminf(fmaxf(x, -7.99881172180175781f), 7.99881172180175781f);
    float x2 = xc * xc;
    float p = -2.76076847742355e-16f;
    p = fmaf(p, x2, 2.00018790482477e-13f);
    p = fmaf(p, x2, -8.60467152213735e-11f);
    p = fmaf(p, x2, 5.12229709037114e-08f);
    p = fmaf(p, x2, 1.48572235717979e-05f);
    p = fmaf(p, x2, 6.37261928875436e-04f);
    p = fmaf(p, x2, 4.89352455891786e-03f);
    float num = xc * p;
    float q = 1.19825839466702e-06f;
    q = fmaf(q, x2, 1.18534705686654e-04f);
    q = fmaf(q, x2, 2.26843463243900e-03f);
    q = fmaf(q, x2, 4.89352518554385e-03f);
    float r = num / q;                       // IEEE f32 divide
    return (ax < 0.0004f) ? x : r;
}

// Correctly-rounded f32 divide for well-scaled normal operands (Markstein).
// No VCC, no denorm-mode s_setreg -> instances interleave freely.
// [bitwise-verified rounds 13-14: absmax 0.0]
__device__ __forceinline__ float div_exact(float a, float b) {
#pragma clang fp contract(off)
    float r = __builtin_amdgcn_rcpf(b);
    float e = fmaf(-b, r, 1.0f);
    r = fmaf(e, r, r);                        // Newton 1
    float e2 = fmaf(-b, r, 1.0f);
    r = fmaf(e2, r, r);                       // Newton 2
    float y = a * r;
    float rem = fmaf(-b, y, a);               // exact residual
    y = fmaf(rem, r, y);                      // fixup 1 (RN result)
    float rem2 = fmaf(-b, y, a);              // exact residual
    y = fmaf(rem2, r, y);                     // fixup 2 (idempotent safety)
    return y;
}

// Packed 2-wide tanh for the hot loop. [bitwise-verified rounds 13-14]
__device__ __forceinline__ v2f xla_tanh2(v2f x) {
#pragma clang fp contract(off)
    const float C = 7.99881172180175781f;
    v2f xc = __builtin_elementwise_min(__builtin_elementwise_max(x, splat2(-C)), splat2(C));
    v2f x2 = xc * xc;
    v2f p = splat2(-2.76076847742355e-16f);
    p = __builtin_elementwise_fma(p, x2, splat2(2.00018790482477e-13f));
    p = __builtin_elementwise_fma(p, x2, splat2(-8.60467152213735e-11f));
    p = __builtin_elementwise_fma(p, x2, splat2(5.12229709037114e-08f));
    p = __builtin_elementwise_fma(p, x2, splat2(1.48572235717979e-05f));
    p = __builtin_elementwise_fma(p, x2, splat2(6.37261928875436e-04f));
    p = __builtin_elementwise_fma(p, x2, splat2(4.89352455891786e-03f));
    v2f num = xc * p;
    v2f q = splat2(1.19825839466702e-06f);
    q = __builtin_elementwise_fma(q, x2, splat2(1.18534705686654e-04f));
    q = __builtin_elementwise_fma(q, x2, splat2(2.26843463243900e-03f));
    q = __builtin_elementwise_fma(q, x2, splat2(4.89352518554385e-03f));
    float rE = div_exact(num.x, q.x);        // == IEEE '/', interleavable
    float rI = div_exact(num.y, q.y);
    v2f r;
    r.x = (fabsf(x.x) < 0.0004f) ? x.x : rE;
    r.y = (fabsf(x.y) < 0.0004f) ? x.y : rI;
    return r;
}

// XLA CPU f32 exp (Cephes/Eigen pexp), FMA-contracted. [bitwise-verified]
__device__ __forceinline__ float xla_expf(float x) {
#pragma clang fp contract(off)
    float xc = fminf(fmaxf(x, -88.3762626647949f), 88.3762626647950f);
    float fx = floorf(fmaf(xc, 1.44269504088896341f, 0.5f));
    float r = fmaf(fx, -0.693359375f, xc);
    r = fmaf(fx, 2.12194440e-4f, r);
    float r2 = r * r;
    float y = 1.9875691500e-4f;
    y = fmaf(y, r, 1.3981999507e-3f);
    y = fmaf(y, r, 8.3334519073e-3f);
    y = fmaf(y, r, 4.1665795894e-2f);
    y = fmaf(y, r, 1.6666665459e-1f);
    y = fmaf(y, r, 5.0000001201e-1f);
    y = fmaf(y, r2, r);
    y = y + 1.0f;
    int n2 = (int)fx;
    float p2n = __int_as_float((n2 + 127) << 23);   // n==-127 -> +0.0
    return y * p2n;
}

// Shared per-element preamble (bitwise-identical everywhere).
__device__ __forceinline__ void preamble(float xv, const float* p,
                                         float& sim0, float& damp, float& omega) {
#pragma clang fp contract(off)
    float mu = p[10], e = p[11], k = p[12];
    float sgn  = (xv > 0.0f) ? 1.0f : ((xv < 0.0f) ? -1.0f : 0.0f);
    sim0 = fmaf(e, sgn, xv);                  // fadd(x, fmul(e,sgn)) fused
    float targ = (-k * sim0) * sim0;          // two plain muls
    damp  = xla_expf(targ);
    omega = xla_tanhf(mu * sim0);
}

// Full predicate (t != 1 and monolithic fallback). PROVEN lemma (round 9).
__device__ __forceinline__ bool fast_omega(float damp, float omega) {
    return (2.0f * damp) < (fabsf(omega) * 0x1p-26f);
}

// t==1 three-way classification on |sim0| (routing only; every route is
// bitwise-correct): 0 = fast (|s|>0.21, PROVEN subset of fast_omega),
// 2 = edge (0.13<|s|<=0.21, slow but period-2-convergent),
// 1 = core (|s|<=0.13, slow, chaotic).
__device__ __forceinline__ int classify3_t1(float xv, float e) {
#pragma clang fp contract(off)
    float sgn  = (xv > 0.0f) ? 1.0f : ((xv < 0.0f) ? -1.0f : 0.0f);
    float sim0 = fmaf(e, sgn, xv);
    float a = fabsf(sim0);
    if (a > 0.21f) return 0;
    if (a > 0.13f) return 2;
    return 1;
}

// ONE verified t1 step — the single source of truth for the hot math.
__device__ __forceinline__ void step_t1(float& E, float& I, float& Dmax, float sim0) {
#pragma clang fp contract(off)
    float tE = 5.0f * E;                   // round(a2*E)  (0*L unfolded)
    v2f mulc; mulc.x = -5.0f; mulc.y = -1.0f;
    v2f iv   = splat2(I);
    v2f addv; addv.x = tE;    addv.y = E;
    v2f u = __builtin_elementwise_fma(mulc, iv, addv);  // (uE, E-I)
    float sE = u.x + sim0;                 // plain fadd (a4==1 folded)
    v2f pre; pre.x = sE; pre.y = u.y;
    v2f args = splat2(5.0f) * pre;         // (argE, argI)
    v2f t = xla_tanh2(args);
    float D = t.x - t.y;                   // plain fsub
    Dmax = fmaxf(Dmax, D);
    E = t.x; I = t.y;
}

// Full 100-step loop (core/chaotic). [bitwise-verified]
__device__ __forceinline__ float loop_t1(float sim0, float damp, float omega) {
#pragma clang fp contract(off)
    float E = 0.2f, I = 0.0f;
    float Dmax = -INFINITY;
    for (int s = 0; s < N_STEPS; ++s) step_t1(E, I, Dmax, sim0);
    return fmaf(Dmax, damp, omega);
}

// Edge loop with EXACT period-2 early exit: if state_t == state_{t-2}
// bitwise, all future states replay {state_{t-1}, state_t} and Dmax is
// final (D_{t+1}=D_{t-1}, D_{t+2}=D_t, both already max'd). Whole-wave
// exit via __all. Identical step math (same step_t1).
__device__ __forceinline__ float loop_t1_edge(float sim0, float damp, float omega) {
#pragma clang fp contract(off)
    float E = 0.2f, I = 0.0f;
    float Dmax = -INFINITY;
    for (int s = 0; s < N_STEPS; s += 2) {
        float Em2 = E, Im2 = I;
        step_t1(E, I, Dmax, sim0);
        step_t1(E, I, Dmax, sim0);
        int per = (__float_as_int(E) == __float_as_int(Em2)) &
                  (__float_as_int(I) == __float_as_int(Im2));
        if (__all(per)) break;
    }
    return fmaf(Dmax, damp, omega);
}

// Generic-type loop (L feedback), proven scalar form (IEEE '/', untouched).
__device__ __forceinline__ float loop_gen(const float* p, float sim0,
                                          float damp, float omega) {
#pragma clang fp contract(off)
    float a1 = p[0], a2 = p[1], a3 = p[2], a4 = p[3];
    float b1 = p[4], b2 = p[5], b3 = p[6], b4 = p[7];
    float xiE = p[8], xiI = p[9], mu = p[10];
    float nb2 = -b2;
    float E = 0.2f, I = 0.0f, L = 0.2f;
    float m = -INFINITY;
    for (int s = 0; s < N_STEPS; ++s) {
        float tE = a2 * E;
        float uE = fmaf(a1, L, tE);
        uE = fmaf(-a3, I, uE);
        uE = fmaf(a4, sim0, uE);
        uE = uE - xiE;
        float argE = mu * uE;
        float tI = nb2 * E;
        float uI = fmaf(b1, L, tI);
        uI = fmaf(-b3, I, uI);
        uI = fmaf(b4, sim0, uI);
        uI = uI - xiI;
        float argI = mu * uI;
        float E1 = xla_tanhf(argE);
        float I1 = xla_tanhf(argI);
        float d = E1 - I1;
        L = fmaf(d, damp, omega);
        E = E1; I = I1;
        m = fmaxf(m, L);
    }
    return m;
}

// Classification shared by k_count / k_fill (must agree EXACTLY).
// Returns 0 fast, 1 core-slow, 2 edge-slow.
__device__ __forceinline__ int classify(float xv, int t, const float* p) {
    if (t == 1) return classify3_t1(xv, p[11]);
    float sim0, damp, omega;
    preamble(xv, p, sim0, damp, omega);
    return fast_omega(damp, omega) ? 0 : 1;
}

// ---------------- kernels ----------------

// 1) per-block counts for both slow classes
__global__ __launch_bounds__(256)
void k_count(const float* __restrict__ x, const int* __restrict__ osc_type,
             unsigned* __restrict__ bcntA, unsigned* __restrict__ bcntB, int n)
{
    __shared__ unsigned wcA[4], wcB[4];
    int i = blockIdx.x * 256 + threadIdx.x;
    int t = *osc_type;
    const float* p = PAR[t - 1];
    int cls = (i < n) ? classify(x[i], t, p) : 0;
    unsigned long long mA = __ballot(cls == 1);
    unsigned long long mB = __ballot(cls == 2);
    int lane = threadIdx.x & 63, wid = threadIdx.x >> 6;
    if (lane == 0) { wcA[wid] = (unsigned)__popcll(mA); wcB[wid] = (unsigned)__popcll(mB); }
    __syncthreads();
    if (threadIdx.x == 0) {
        bcntA[blockIdx.x] = wcA[0] + wcA[1] + wcA[2] + wcA[3];
        bcntB[blockIdx.x] = wcB[0] + wcB[1] + wcB[2] + wcB[3];
    }
}

// 2) fill: self-scan both count arrays; fast -> out = omega; core -> wl
//    front; edge -> wl back; last block writes totals to bcnt*[NB].
__global__ __launch_bounds__(256)
void k_fill(const float* __restrict__ x, const int* __restrict__ osc_type,
            float* __restrict__ out, unsigned* __restrict__ bcntA,
            unsigned* __restrict__ bcntB, unsigned* __restrict__ wl,
            int n, int NB)
{
#pragma clang fp contract(off)
    __shared__ unsigned sumsA[256], sumsB[256];
    __shared__ unsigned woffA[4], woffB[4];
    int tid = threadIdx.x;
    int bid = blockIdx.x;

    unsigned sA = 0, sB = 0;
    for (int j = tid; j < bid; j += 256) { sA += bcntA[j]; sB += bcntB[j]; }
    sumsA[tid] = sA; sumsB[tid] = sB;
    __syncthreads();
    for (int off = 128; off > 0; off >>= 1) {
        if (tid < off) { sumsA[tid] += sumsA[tid + off]; sumsB[tid] += sumsB[tid + off]; }
        __syncthreads();
    }
    unsigned baseA = sumsA[0], baseB = sumsB[0];

    int i = bid * 256 + tid;
    bool active = (i < n);
    int t = *osc_type;
    const float* p = PAR[t - 1];
    float xv = active ? x[i] : 1.0e9f;          // 1e9 -> fast (and inactive)
    int cls = active ? classify(xv, t, p) : 0;
    if (active && cls == 0) {
        float mu = p[10], e = p[11];
        float sgn  = (xv > 0.0f) ? 1.0f : ((xv < 0.0f) ? -1.0f : 0.0f);
        float sim0 = fmaf(e, sgn, xv);
        out[i] = xla_tanhf(mu * sim0);          // omega, exactly as preamble
    }
    unsigned long long mA = __ballot(cls == 1);
    unsigned long long mB = __ballot(cls == 2);
    int lane = tid & 63, wid = tid >> 6;
    if (lane == 0) { woffA[wid] = (unsigned)__popcll(mA); woffB[wid] = (unsigned)__popcll(mB); }
    __syncthreads();
    unsigned long long below = (1ull << lane) - 1ull;
    if (cls == 1) {
        unsigned pos = baseA;
        for (int w = 0; w < wid; ++w) pos += woffA[w];
        pos += (unsigned)__popcll(mA & below);
        wl[pos] = (unsigned)i;
    } else if (cls == 2) {
        unsigned pos = baseB;
        for (int w = 0; w < wid; ++w) pos += woffB[w];
        pos += (unsigned)__popcll(mB & below);
        wl[(unsigned)n - 1u - pos] = (unsigned)i;   // edge grows from the back
    }
    if (tid == 0 && bid == NB - 1) {
        bcntA[NB] = baseA + woffA[0] + woffA[1] + woffA[2] + woffA[3];
        bcntB[NB] = baseB + woffB[0] + woffB[1] + woffB[2] + woffB[3];
    }
}

// 3) dense worklists: 1 elem/thread (R13-proven shape). tid<Tc -> core
//    (full 100 steps); else edge (period-2 early exit). Band-contiguous
//    lists keep waves homogeneous so __all() fires.
__global__ __launch_bounds__(64)
void k_process(const float* __restrict__ x, const int* __restrict__ osc_type,
               float* __restrict__ out, const unsigned* __restrict__ bcntA,
               const unsigned* __restrict__ bcntB, const unsigned* __restrict__ wl,
               int n, int NB)
{
#pragma clang fp contract(off)
    unsigned Tc = bcntA[NB];
    unsigned Te = bcntB[NB];
    unsigned total = Tc + Te;
    int t = *osc_type;
    const float* p = PAR[t - 1];
    unsigned stride = gridDim.x * 64u;
    for (unsigned tid = blockIdx.x * 64u + threadIdx.x; tid < total; tid += stride) {
        if (t == 1) {
            if (tid < Tc) {
                int i = (int)wl[tid];
                float sim0, damp, omega;
                preamble(x[i], p, sim0, damp, omega);
                out[i] = loop_t1(sim0, damp, omega);
            } else {
                int i = (int)wl[(unsigned)n - 1u - (tid - Tc)];
                float sim0, damp, omega;
                preamble(x[i], p, sim0, damp, omega);
                out[i] = loop_t1_edge(sim0, damp, omega);
            }
        } else {
            int i = (int)wl[tid];
            float sim0, damp, omega;
            preamble(x[i], p, sim0, damp, omega);
            out[i] = loop_gen(p, sim0, damp, omega);
        }
    }
}

// Fallback: proven monolithic kernel (if ws too small).
__global__ __launch_bounds__(256)
void k_monolithic(const float* __restrict__ x, const int* __restrict__ osc_type,
                  float* __restrict__ out, int n)
{
#pragma clang fp contract(off)
    int i = blockIdx.x * 256 + threadIdx.x;
    if (i >= n) return;
    int t = *osc_type;
    const float* p = PAR[t - 1];
    float sim0, damp, omega;
    preamble(x[i], p, sim0, damp, omega);
    if (fast_omega(damp, omega)) { out[i] = omega; return; }
    out[i] = (t == 1) ? loop_t1(sim0, damp, omega)
                      : loop_gen(p, sim0, damp, omega);
}

extern "C" void kernel_launch(void* const* d_in, const int* in_sizes, int n_in,
                              void* d_out, int out_size, void* d_ws, size_t ws_size,
                              hipStream_t stream) {
    const float* x        = (const float*)d_in[0];
    const int*   osc_type = (const int*)d_in[1];
    float*       out      = (float*)d_out;
    int n = in_sizes[0];
    int NB = (n + 255) / 256;

    size_t needed = (2 * ((size_t)NB + 1) + (size_t)n) * sizeof(unsigned);
    if (ws_size >= needed) {
        unsigned* bcntA = (unsigned*)d_ws;       // NB+1 ([NB] = core total)
        unsigned* bcntB = bcntA + NB + 1;        // NB+1 ([NB] = edge total)
        unsigned* wl    = bcntB + NB + 1;        // n entries
        k_count  <<<NB, 256, 0, stream>>>(x, osc_type, bcntA, bcntB, n);
        k_fill   <<<NB, 256, 0, stream>>>(x, osc_type, out, bcntA, bcntB, wl, n, NB);
        k_process<<<4096, 64, 0, stream>>>(x, osc_type, out, bcntA, bcntB, wl, n, NB);
    } else {
        k_monolithic<<<NB, 256, 0, stream>>>(x, osc_type, out, n);
    }
}

// Round 16
// 42.029 us; speedup vs baseline: 1.1795x; 1.1795x over previous
//
#include <hip/hip_runtime.h>
#include <math.h>

// Lee Oscillator: per-element 100-step chaotic recurrence, time-max-pooled.
// Bitwise-matches jax/XLA-CPU f32 semantics (PROVEN: rounds 6-15 absmax=0.0).
// The arithmetic (xla_tanhf/xla_expf/div/fusion pattern) must not change.
//
// Round-16: revert to the R13 structure (best: 43.3us; R15's period-2 exit
// regressed — float orbits don't become bitwise-periodic reliably). New:
// pack the LAST unpacked hot-loop ops — the two scalar div_exact calls
// (~20 of ~48 instr/step) — into div2_exact: 2x v_rcp + packed v_pk_fma
// Newton/fixup, per-component op order identical => bitwise by construction.
// Drop the idempotent 2nd Markstein fixup (1 fixup after 2 Newtons is RN;
// absmax over 34.6M chaotic divides is the verifier — revert if != 0).

#define N_STEPS 100

typedef float v2f __attribute__((ext_vector_type(2)));
__device__ __forceinline__ v2f splat2(float s){ v2f v; v.x = s; v.y = s; return v; }

// (a1,a2,a3,a4,b1,b2,b3,b4,xi_E,xi_I,mu,e,k) for oscillator types 1..8 (f32)
__constant__ float PAR[8][13] = {
    { 0.0f,  5.0f,  5.0f,  1.0f,  0.0f, -1.0f,  1.0f,  0.0f, 0.0f, 0.0f, 5.0f, 0.001f, 500.0f},
    { 0.5f,  0.55f, 0.55f, -0.5f,  0.5f, -0.55f, -0.55f, -0.5f, 0.0f, 0.0f, 1.0f, 0.001f, 50.0f},
    { 0.5f,  0.6f,  0.55f,  0.5f, -0.5f, -0.6f,  -0.55f,  0.5f, 0.0f, 0.0f, 1.0f, 0.001f, 50.0f},
    {-0.5f,  0.55f, 0.55f, -0.5f, -0.5f, -0.55f, -0.55f,  0.5f, 0.0f, 0.0f, 1.0f, 0.001f, 50.0f},
    {-0.9f,  0.9f,  0.9f,  -0.9f,  0.9f, -0.9f,  -0.9f,   0.9f, 0.0f, 0.0f, 1.0f, 0.001f, 50.0f},
    {-0.9f,  0.9f,  0.9f,  -0.9f,  0.9f, -0.9f,  -0.9f,   0.9f, 0.0f, 0.0f, 1.0f, 0.001f, 300.0f},
    {-5.0f,  5.0f,  5.0f,  -5.0f,  1.0f, -1.0f,  -1.0f,   1.0f, 0.0f, 0.0f, 1.0f, 0.001f, 50.0f},
    {-5.0f,  5.0f,  5.0f,  -5.0f,  1.0f, -1.0f,  -1.0f,   1.0f, 0.0f, 0.0f, 1.0f, 0.001f, 300.0f},
};

// XLA CPU f32 tanh — scalar form with IEEE '/'. Used OUTSIDE the hot loop
// (preamble/omega/classification). [bitwise-verified rounds 6-15]
__device__ __forceinline__ float xla_tanhf(float x) {
#pragma clang fp contract(off)
    float ax = fabsf(x);
    float xc = fminf(fmaxf(x, -7.99881172180175781f), 7.99881172180175781f);
    float x2 = xc * xc;
    float p = -2.76076847742355e-16f;
    p = fmaf(p, x2, 2.00018790482477e-13f);
    p = fmaf(p, x2, -8.60467152213735e-11f);
    p = fmaf(p, x2, 5.12229709037114e-08f);
    p = fmaf(p, x2, 1.48572235717979e-05f);
    p = fmaf(p, x2, 6.37261928875436e-04f);
    p = fmaf(p, x2, 4.89352455891786e-03f);
    float num = xc * p;
    float q = 1.19825839466702e-06f;
    q = fmaf(q, x2, 1.18534705686654e-04f);
    q = fmaf(q, x2, 2.26843463243900e-03f);
    q = fmaf(q, x2, 4.89352518554385e-03f);
    float r = num / q;                       // IEEE f32 divide
    return (ax < 0.0004f) ? x : r;
}

// Packed correctly-rounded divide (Markstein) for the hot loop's well-scaled
// operands (q in [4.89e-3,0.94], used |num| in [2e-6,0.95]):
// 2x scalar v_rcp + packed Newton x2 + exact residual + ONE fixup -> RN
// quotient == IEEE '/'. Per-component op order identical to the verified
// scalar div_exact (minus the idempotent 2nd fixup). No VCC / mode traffic.
__device__ __forceinline__ v2f div2_exact(v2f a, v2f b) {
#pragma clang fp contract(off)
    v2f r;
    r.x = __builtin_amdgcn_rcpf(b.x);
    r.y = __builtin_amdgcn_rcpf(b.y);
    v2f one = splat2(1.0f);
    v2f nb; nb.x = -b.x; nb.y = -b.y;                 // exact sign flip
    v2f e  = __builtin_elementwise_fma(nb, r, one);
    r = __builtin_elementwise_fma(e, r, r);           // Newton 1
    v2f e2 = __builtin_elementwise_fma(nb, r, one);
    r = __builtin_elementwise_fma(e2, r, r);          // Newton 2
    v2f y = a * r;
    v2f rem = __builtin_elementwise_fma(nb, y, a);    // exact residual
    y = __builtin_elementwise_fma(rem, r, y);         // Markstein fixup -> RN
    return y;
}

// Packed 2-wide tanh for the hot loop: SAME per-component IEEE ops,
// fully pk-packed including the divide. [poly verified rounds 8-15]
__device__ __forceinline__ v2f xla_tanh2(v2f x) {
#pragma clang fp contract(off)
    const float C = 7.99881172180175781f;
    v2f xc = __builtin_elementwise_min(__builtin_elementwise_max(x, splat2(-C)), splat2(C));
    v2f x2 = xc * xc;
    v2f p = splat2(-2.76076847742355e-16f);
    p = __builtin_elementwise_fma(p, x2, splat2(2.00018790482477e-13f));
    p = __builtin_elementwise_fma(p, x2, splat2(-8.60467152213735e-11f));
    p = __builtin_elementwise_fma(p, x2, splat2(5.12229709037114e-08f));
    p = __builtin_elementwise_fma(p, x2, splat2(1.48572235717979e-05f));
    p = __builtin_elementwise_fma(p, x2, splat2(6.37261928875436e-04f));
    p = __builtin_elementwise_fma(p, x2, splat2(4.89352455891786e-03f));
    v2f num = xc * p;
    v2f q = splat2(1.19825839466702e-06f);
    q = __builtin_elementwise_fma(q, x2, splat2(1.18534705686654e-04f));
    q = __builtin_elementwise_fma(q, x2, splat2(2.26843463243900e-03f));
    q = __builtin_elementwise_fma(q, x2, splat2(4.89352518554385e-03f));
    v2f d = div2_exact(num, q);              // == IEEE '/' per component
    v2f r;
    r.x = (fabsf(x.x) < 0.0004f) ? x.x : d.x;
    r.y = (fabsf(x.y) < 0.0004f) ? x.y : d.y;
    return r;
}

// XLA CPU f32 exp (Cephes/Eigen pexp), FMA-contracted. [bitwise-verified]
__device__ __forceinline__ float xla_expf(float x) {
#pragma clang fp contract(off)
    float xc = fminf(fmaxf(x, -88.3762626647949f), 88.3762626647950f);
    float fx = floorf(fmaf(xc, 1.44269504088896341f, 0.5f));
    float r = fmaf(fx, -0.693359375f, xc);
    r = fmaf(fx, 2.12194440e-4f, r);
    float r2 = r * r;
    float y = 1.9875691500e-4f;
    y = fmaf(y, r, 1.3981999507e-3f);
    y = fmaf(y, r, 8.3334519073e-3f);
    y = fmaf(y, r, 4.1665795894e-2f);
    y = fmaf(y, r, 1.6666665459e-1f);
    y = fmaf(y, r, 5.0000001201e-1f);
    y = fmaf(y, r2, r);
    y = y + 1.0f;
    int n2 = (int)fx;
    float p2n = __int_as_float((n2 + 127) << 23);   // n==-127 -> +0.0
    return y * p2n;
}

// Shared per-element preamble (bitwise-identical everywhere).
__device__ __forceinline__ void preamble(float xv, const float* p,
                                         float& sim0, float& damp, float& omega) {
#pragma clang fp contract(off)
    float mu = p[10], e = p[11], k = p[12];
    float sgn  = (xv > 0.0f) ? 1.0f : ((xv < 0.0f) ? -1.0f : 0.0f);
    sim0 = fmaf(e, sgn, xv);                  // fadd(x, fmul(e,sgn)) fused
    float targ = (-k * sim0) * sim0;          // two plain muls
    damp  = xla_expf(targ);
    omega = xla_tanhf(mu * sim0);
}

// Full predicate (t != 1 and monolithic fallback). PROVEN lemma (round 9):
// 2*damp < |omega|*2^-26 with |D|<2 => fma(D,damp,omega)==omega every step.
__device__ __forceinline__ bool fast_omega(float damp, float omega) {
    return (2.0f * damp) < (fabsf(omega) * 0x1p-26f);
}

// t==1 cheap classification: slow iff |sim0| <= 0.21. PROVEN subset of the
// predicate above (22x margin at the boundary, grows like e^{500(s^2-0.0441)}).
// Slow-side routing is always correctness-neutral (loop returns omega).
__device__ __forceinline__ bool slow_t1(float xv, float e) {
#pragma clang fp contract(off)
    float sgn  = (xv > 0.0f) ? 1.0f : ((xv < 0.0f) ? -1.0f : 0.0f);
    float sim0 = fmaf(e, sgn, xv);
    return fabsf(sim0) <= 0.21f;
}

// 100-step loop, type-1 specialization (a1=b1=0, a4=1, xi=0), pk-packed.
// Per-component ops bitwise-identical to the round-6 verified scalar loop.
__device__ __forceinline__ float loop_t1(float sim0, float damp, float omega) {
#pragma clang fp contract(off)
    float E = 0.2f, I = 0.0f;
    float Dmax = -INFINITY;
    for (int s = 0; s < N_STEPS; ++s) {
        float tE = 5.0f * E;                   // round(a2*E)  (0*L unfolded)
        v2f mulc; mulc.x = -5.0f; mulc.y = -1.0f;
        v2f iv   = splat2(I);
        v2f addv; addv.x = tE;    addv.y = E;
        v2f u = __builtin_elementwise_fma(mulc, iv, addv);  // (uE, E-I)
        float sE = u.x + sim0;                 // plain fadd (a4==1 folded)
        v2f pre; pre.x = sE; pre.y = u.y;
        v2f args = splat2(5.0f) * pre;         // (argE, argI)
        v2f t = xla_tanh2(args);
        float D = t.x - t.y;                   // plain fsub
        Dmax = fmaxf(Dmax, D);
        E = t.x; I = t.y;
    }
    return fmaf(Dmax, damp, omega);            // == max_t fma(D_t,damp,omega)
}

// Generic-type loop (L feedback), proven scalar form (IEEE '/', untouched).
__device__ __forceinline__ float loop_gen(const float* p, float sim0,
                                          float damp, float omega) {
#pragma clang fp contract(off)
    float a1 = p[0], a2 = p[1], a3 = p[2], a4 = p[3];
    float b1 = p[4], b2 = p[5], b3 = p[6], b4 = p[7];
    float xiE = p[8], xiI = p[9], mu = p[10];
    float nb2 = -b2;
    float E = 0.2f, I = 0.0f, L = 0.2f;
    float m = -INFINITY;
    for (int s = 0; s < N_STEPS; ++s) {
        float tE = a2 * E;
        float uE = fmaf(a1, L, tE);
        uE = fmaf(-a3, I, uE);
        uE = fmaf(a4, sim0, uE);
        uE = uE - xiE;
        float argE = mu * uE;
        float tI = nb2 * E;
        float uI = fmaf(b1, L, tI);
        uI = fmaf(-b3, I, uI);
        uI = fmaf(b4, sim0, uI);
        uI = uI - xiI;
        float argI = mu * uI;
        float E1 = xla_tanhf(argE);
        float I1 = xla_tanhf(argI);
        float d = E1 - I1;
        L = fmaf(d, damp, omega);
        E = E1; I = I1;
        m = fmaxf(m, L);
    }
    return m;
}

// Classification shared by k_count / k_fill (must agree EXACTLY).
__device__ __forceinline__ bool classify_slow(float xv, int t, const float* p) {
    if (t == 1) return slow_t1(xv, p[11]);
    float sim0, damp, omega;
    preamble(xv, p, sim0, damp, omega);
    return !fast_omega(damp, omega);
}

// ---------------- kernels ----------------

// 1) per-block slow-lane count (ballot + popc, no atomics)
__global__ __launch_bounds__(256)
void k_count(const float* __restrict__ x, const int* __restrict__ osc_type,
             unsigned* __restrict__ bcount, int n)
{
    __shared__ unsigned wc[4];
    int i = blockIdx.x * 256 + threadIdx.x;
    int t = *osc_type;
    const float* p = PAR[t - 1];
    bool slow = (i < n) && classify_slow(x[i], t, p);
    unsigned long long mask = __ballot(slow);
    int lane = threadIdx.x & 63, wid = threadIdx.x >> 6;
    if (lane == 0) wc[wid] = (unsigned)__popcll(mask);
    __syncthreads();
    if (threadIdx.x == 0) bcount[blockIdx.x] = wc[0] + wc[1] + wc[2] + wc[3];
}

// 2) fill: self-scan bcount for this block's base; fast lanes -> out=omega;
//    slow lanes -> wl[base + local prefix]; last block writes bcount[NB]=total.
__global__ __launch_bounds__(256)
void k_fill(const float* __restrict__ x, const int* __restrict__ osc_type,
            float* __restrict__ out, unsigned* __restrict__ bcount,
            unsigned* __restrict__ wl, int n, int NB)
{
#pragma clang fp contract(off)
    __shared__ unsigned sums[256];
    __shared__ unsigned woff[4];
    int tid = threadIdx.x;
    int bid = blockIdx.x;

    // self-scan: base = sum of bcount[0..bid)
    unsigned s = 0;
    for (int j = tid; j < bid; j += 256) s += bcount[j];
    sums[tid] = s;
    __syncthreads();
    for (int off = 128; off > 0; off >>= 1) {
        if (tid < off) sums[tid] += sums[tid + off];
        __syncthreads();
    }
    unsigned bbase = sums[0];

    int i = bid * 256 + tid;
    bool active = (i < n);
    int t = *osc_type;
    const float* p = PAR[t - 1];
    float xv = active ? x[i] : 1.0e9f;          // 1e9 -> fast (and inactive)
    bool slow = active && classify_slow(xv, t, p);
    if (active && !slow) {
        // omega, computed exactly as in preamble
        float mu = p[10], e = p[11];
        float sgn  = (xv > 0.0f) ? 1.0f : ((xv < 0.0f) ? -1.0f : 0.0f);
        float sim0 = fmaf(e, sgn, xv);
        out[i] = xla_tanhf(mu * sim0);
    }
    unsigned long long mask = __ballot(slow);
    int lane = tid & 63, wid = tid >> 6;
    if (lane == 0) woff[wid] = (unsigned)__popcll(mask);
    __syncthreads();
    if (slow) {
        unsigned base = bbase;
        for (int w = 0; w < wid; ++w) base += woff[w];
        base += (unsigned)__popcll(mask & ((1ull << lane) - 1ull));
        wl[base] = (unsigned)i;
    }
    if (tid == 0 && bid == NB - 1)
        bcount[NB] = bbase + woff[0] + woff[1] + woff[2] + woff[3];
}

// 3) dense worklist: 1 element/thread (best issue efficiency), 64-thread
//    workgroups for finest CU balance, grid-stride for safety.
__global__ __launch_bounds__(64)
void k_process(const float* __restrict__ x, const int* __restrict__ osc_type,
               float* __restrict__ out, const unsigned* __restrict__ total_p,
               const unsigned* __restrict__ wl)
{
#pragma clang fp contract(off)
    unsigned total = *total_p;
    int t = *osc_type;
    const float* p = PAR[t - 1];
    unsigned stride = gridDim.x * 64u;
    for (unsigned tid = blockIdx.x * 64u + threadIdx.x; tid < total; tid += stride) {
        int i = (int)wl[tid];
        float sim0, damp, omega;
        preamble(x[i], p, sim0, damp, omega);
        out[i] = (t == 1) ? loop_t1(sim0, damp, omega)
                          : loop_gen(p, sim0, damp, omega);
    }
}

// Fallback: proven monolithic kernel (if ws too small).
__global__ __launch_bounds__(256)
void k_monolithic(const float* __restrict__ x, const int* __restrict__ osc_type,
                  float* __restrict__ out, int n)
{
#pragma clang fp contract(off)
    int i = blockIdx.x * 256 + threadIdx.x;
    if (i >= n) return;
    int t = *osc_type;
    const float* p = PAR[t - 1];
    float sim0, damp, omega;
    preamble(x[i], p, sim0, damp, omega);
    if (fast_omega(damp, omega)) { out[i] = omega; return; }
    out[i] = (t == 1) ? loop_t1(sim0, damp, omega)
                      : loop_gen(p, sim0, damp, omega);
}

extern "C" void kernel_launch(void* const* d_in, const int* in_sizes, int n_in,
                              void* d_out, int out_size, void* d_ws, size_t ws_size,
                              hipStream_t stream) {
    const float* x        = (const float*)d_in[0];
    const int*   osc_type = (const int*)d_in[1];
    float*       out      = (float*)d_out;
    int n = in_sizes[0];
    int NB = (n + 255) / 256;

    size_t needed = ((size_t)NB + 1 + (size_t)n) * sizeof(unsigned);
    if (ws_size >= needed) {
        unsigned* bcount = (unsigned*)d_ws;      // NB+1 entries ([NB] = total)
        unsigned* wl     = bcount + NB + 1;      // n entries
        k_count  <<<NB, 256, 0, stream>>>(x, osc_type, bcount, n);
        k_fill   <<<NB, 256, 0, stream>>>(x, osc_type, out, bcount, wl, n, NB);
        k_process<<<4096, 64, 0, stream>>>(x, osc_type, out, bcount + NB, wl);
    } else {
        k_monolithic<<<NB, 256, 0, stream>>>(x, osc_type, out, n);
    }
}

// Round 17
// 40.990 us; speedup vs baseline: 1.2094x; 1.0253x over previous
//
#include <hip/hip_runtime.h>
#include <math.h>

// Lee Oscillator: per-element 100-step chaotic recurrence, time-max-pooled.
// Bitwise-matches jax/XLA-CPU f32 semantics (PROVEN: rounds 6-16 absmax=0.0).
// The arithmetic (xla_tanhf/xla_expf/div2_exact/fusion pattern) must not change.
//
// Round-17: ONE fused kernel (was count+fill+process = ~9us overhead).
// Per 256-thread block: phase1 (4 waves) = preamble all elements, write
// omega for fast lanes, ballot+prefix-compact slow (idx,sim0,damp,omega)
// into LDS. syncthreads. Waves 1-3 EXIT; wave 0 runs the proven 100-step
// loop over the block's S slow elems (S ~ Binomial(256,0.165) ~= 42 < 64).
// Busy loop-waves: 4096 (vs 2704) at ~66% lane-occupancy — fine, we are
// latency-bound not issue-bound. No atomics, no workspace, deterministic.

#define N_STEPS 100

typedef float v2f __attribute__((ext_vector_type(2)));
__device__ __forceinline__ v2f splat2(float s){ v2f v; v.x = s; v.y = s; return v; }

// (a1,a2,a3,a4,b1,b2,b3,b4,xi_E,xi_I,mu,e,k) for oscillator types 1..8 (f32)
__constant__ float PAR[8][13] = {
    { 0.0f,  5.0f,  5.0f,  1.0f,  0.0f, -1.0f,  1.0f,  0.0f, 0.0f, 0.0f, 5.0f, 0.001f, 500.0f},
    { 0.5f,  0.55f, 0.55f, -0.5f,  0.5f, -0.55f, -0.55f, -0.5f, 0.0f, 0.0f, 1.0f, 0.001f, 50.0f},
    { 0.5f,  0.6f,  0.55f,  0.5f, -0.5f, -0.6f,  -0.55f,  0.5f, 0.0f, 0.0f, 1.0f, 0.001f, 50.0f},
    {-0.5f,  0.55f, 0.55f, -0.5f, -0.5f, -0.55f, -0.55f,  0.5f, 0.0f, 0.0f, 1.0f, 0.001f, 50.0f},
    {-0.9f,  0.9f,  0.9f,  -0.9f,  0.9f, -0.9f,  -0.9f,   0.9f, 0.0f, 0.0f, 1.0f, 0.001f, 50.0f},
    {-0.9f,  0.9f,  0.9f,  -0.9f,  0.9f, -0.9f,  -0.9f,   0.9f, 0.0f, 0.0f, 1.0f, 0.001f, 300.0f},
    {-5.0f,  5.0f,  5.0f,  -5.0f,  1.0f, -1.0f,  -1.0f,   1.0f, 0.0f, 0.0f, 1.0f, 0.001f, 50.0f},
    {-5.0f,  5.0f,  5.0f,  -5.0f,  1.0f, -1.0f,  -1.0f,   1.0f, 0.0f, 0.0f, 1.0f, 0.001f, 300.0f},
};

// XLA CPU f32 tanh — scalar form with IEEE '/'. Used in the preamble.
// [bitwise-verified rounds 6-16]
__device__ __forceinline__ float xla_tanhf(float x) {
#pragma clang fp contract(off)
    float ax = fabsf(x);
    float xc = fminf(fmaxf(x, -7.99881172180175781f), 7.99881172180175781f);
    float x2 = xc * xc;
    float p = -2.76076847742355e-16f;
    p = fmaf(p, x2, 2.00018790482477e-13f);
    p = fmaf(p, x2, -8.60467152213735e-11f);
    p = fmaf(p, x2, 5.12229709037114e-08f);
    p = fmaf(p, x2, 1.48572235717979e-05f);
    p = fmaf(p, x2, 6.37261928875436e-04f);
    p = fmaf(p, x2, 4.89352455891786e-03f);
    float num = xc * p;
    float q = 1.19825839466702e-06f;
    q = fmaf(q, x2, 1.18534705686654e-04f);
    q = fmaf(q, x2, 2.26843463243900e-03f);
    q = fmaf(q, x2, 4.89352518554385e-03f);
    float r = num / q;                       // IEEE f32 divide
    return (ax < 0.0004f) ? x : r;
}

// Packed correctly-rounded divide (Markstein) for the hot loop's well-scaled
// operands. [bitwise-verified round 16: absmax 0.0 over 34.6M chaotic divides]
__device__ __forceinline__ v2f div2_exact(v2f a, v2f b) {
#pragma clang fp contract(off)
    v2f r;
    r.x = __builtin_amdgcn_rcpf(b.x);
    r.y = __builtin_amdgcn_rcpf(b.y);
    v2f one = splat2(1.0f);
    v2f nb; nb.x = -b.x; nb.y = -b.y;                 // exact sign flip
    v2f e  = __builtin_elementwise_fma(nb, r, one);
    r = __builtin_elementwise_fma(e, r, r);           // Newton 1
    v2f e2 = __builtin_elementwise_fma(nb, r, one);
    r = __builtin_elementwise_fma(e2, r, r);          // Newton 2
    v2f y = a * r;
    v2f rem = __builtin_elementwise_fma(nb, y, a);    // exact residual
    y = __builtin_elementwise_fma(rem, r, y);         // Markstein fixup -> RN
    return y;
}

// Packed 2-wide tanh for the hot loop. [bitwise-verified rounds 13-16]
__device__ __forceinline__ v2f xla_tanh2(v2f x) {
#pragma clang fp contract(off)
    const float C = 7.99881172180175781f;
    v2f xc = __builtin_elementwise_min(__builtin_elementwise_max(x, splat2(-C)), splat2(C));
    v2f x2 = xc * xc;
    v2f p = splat2(-2.76076847742355e-16f);
    p = __builtin_elementwise_fma(p, x2, splat2(2.00018790482477e-13f));
    p = __builtin_elementwise_fma(p, x2, splat2(-8.60467152213735e-11f));
    p = __builtin_elementwise_fma(p, x2, splat2(5.12229709037114e-08f));
    p = __builtin_elementwise_fma(p, x2, splat2(1.48572235717979e-05f));
    p = __builtin_elementwise_fma(p, x2, splat2(6.37261928875436e-04f));
    p = __builtin_elementwise_fma(p, x2, splat2(4.89352455891786e-03f));
    v2f num = xc * p;
    v2f q = splat2(1.19825839466702e-06f);
    q = __builtin_elementwise_fma(q, x2, splat2(1.18534705686654e-04f));
    q = __builtin_elementwise_fma(q, x2, splat2(2.26843463243900e-03f));
    q = __builtin_elementwise_fma(q, x2, splat2(4.89352518554385e-03f));
    v2f d = div2_exact(num, q);              // == IEEE '/' per component
    v2f r;
    r.x = (fabsf(x.x) < 0.0004f) ? x.x : d.x;
    r.y = (fabsf(x.y) < 0.0004f) ? x.y : d.y;
    return r;
}

// XLA CPU f32 exp (Cephes/Eigen pexp), FMA-contracted. [bitwise-verified]
__device__ __forceinline__ float xla_expf(float x) {
#pragma clang fp contract(off)
    float xc = fminf(fmaxf(x, -88.3762626647949f), 88.3762626647950f);
    float fx = floorf(fmaf(xc, 1.44269504088896341f, 0.5f));
    float r = fmaf(fx, -0.693359375f, xc);
    r = fmaf(fx, 2.12194440e-4f, r);
    float r2 = r * r;
    float y = 1.9875691500e-4f;
    y = fmaf(y, r, 1.3981999507e-3f);
    y = fmaf(y, r, 8.3334519073e-3f);
    y = fmaf(y, r, 4.1665795894e-2f);
    y = fmaf(y, r, 1.6666665459e-1f);
    y = fmaf(y, r, 5.0000001201e-1f);
    y = fmaf(y, r2, r);
    y = y + 1.0f;
    int n2 = (int)fx;
    float p2n = __int_as_float((n2 + 127) << 23);   // n==-127 -> +0.0
    return y * p2n;
}

// Shared per-element preamble (bitwise-identical everywhere).
__device__ __forceinline__ void preamble(float xv, const float* p,
                                         float& sim0, float& damp, float& omega) {
#pragma clang fp contract(off)
    float mu = p[10], e = p[11], k = p[12];
    float sgn  = (xv > 0.0f) ? 1.0f : ((xv < 0.0f) ? -1.0f : 0.0f);
    sim0 = fmaf(e, sgn, xv);                  // fadd(x, fmul(e,sgn)) fused
    float targ = (-k * sim0) * sim0;          // two plain muls
    damp  = xla_expf(targ);
    omega = xla_tanhf(mu * sim0);
}

// Full predicate (t != 1). PROVEN lemma (round 9):
// 2*damp < |omega|*2^-26 with |D|<2 => fma(D,damp,omega)==omega every step.
__device__ __forceinline__ bool fast_omega(float damp, float omega) {
    return (2.0f * damp) < (fabsf(omega) * 0x1p-26f);
}

// t==1 cheap classification: slow iff |sim0| <= 0.21. PROVEN subset of the
// predicate above (22x margin at the boundary). Slow-side routing is always
// correctness-neutral (loop returns omega bitwise).
__device__ __forceinline__ bool slow_t1_from_sim0(float sim0) {
    return fabsf(sim0) <= 0.21f;
}

// 100-step loop, type-1 specialization (a1=b1=0, a4=1, xi=0), pk-packed.
// [bitwise-verified round 16 incl. packed divide]
__device__ __forceinline__ float loop_t1(float sim0, float damp, float omega) {
#pragma clang fp contract(off)
    float E = 0.2f, I = 0.0f;
    float Dmax = -INFINITY;
    for (int s = 0; s < N_STEPS; ++s) {
        float tE = 5.0f * E;                   // round(a2*E)  (0*L unfolded)
        v2f mulc; mulc.x = -5.0f; mulc.y = -1.0f;
        v2f iv   = splat2(I);
        v2f addv; addv.x = tE;    addv.y = E;
        v2f u = __builtin_elementwise_fma(mulc, iv, addv);  // (uE, E-I)
        float sE = u.x + sim0;                 // plain fadd (a4==1 folded)
        v2f pre; pre.x = sE; pre.y = u.y;
        v2f args = splat2(5.0f) * pre;         // (argE, argI)
        v2f t = xla_tanh2(args);
        float D = t.x - t.y;                   // plain fsub
        Dmax = fmaxf(Dmax, D);
        E = t.x; I = t.y;
    }
    return fmaf(Dmax, damp, omega);            // == max_t fma(D_t,damp,omega)
}

// Generic-type loop (L feedback), proven scalar form (IEEE '/', untouched).
__device__ __forceinline__ float loop_gen(const float* p, float sim0,
                                          float damp, float omega) {
#pragma clang fp contract(off)
    float a1 = p[0], a2 = p[1], a3 = p[2], a4 = p[3];
    float b1 = p[4], b2 = p[5], b3 = p[6], b4 = p[7];
    float xiE = p[8], xiI = p[9], mu = p[10];
    float nb2 = -b2;
    float E = 0.2f, I = 0.0f, L = 0.2f;
    float m = -INFINITY;
    for (int s = 0; s < N_STEPS; ++s) {
        float tE = a2 * E;
        float uE = fmaf(a1, L, tE);
        uE = fmaf(-a3, I, uE);
        uE = fmaf(a4, sim0, uE);
        uE = uE - xiE;
        float argE = mu * uE;
        float tI = nb2 * E;
        float uI = fmaf(b1, L, tI);
        uI = fmaf(-b3, I, uI);
        uI = fmaf(b4, sim0, uI);
        uI = uI - xiI;
        float argI = mu * uI;
        float E1 = xla_tanhf(argE);
        float I1 = xla_tanhf(argI);
        float d = E1 - I1;
        L = fmaf(d, damp, omega);
        E = E1; I = I1;
        m = fmaxf(m, L);
    }
    return m;
}

// ---------------- single fused kernel ----------------
// Phase1 (4 waves): preamble, fast->out=omega, block-compact slow to LDS.
// Phase2 (wave 0 only): 100-step loop over the block's S slow elements.
__global__ __launch_bounds__(256)
void k_fused(const float* __restrict__ x, const int* __restrict__ osc_type,
             float* __restrict__ out, int n)
{
#pragma clang fp contract(off)
    __shared__ unsigned wc[4];
    __shared__ unsigned sidx[256];
    __shared__ float    ssim[256], sdamp[256], somega[256];

    int tid = threadIdx.x;
    int i = blockIdx.x * 256 + tid;
    bool active = (i < n);
    int t = *osc_type;
    const float* p = PAR[t - 1];

    float xv = active ? x[i] : 1.0e9f;        // 1e9 -> fast (and inactive)
    float sim0, damp, omega;
    preamble(xv, p, sim0, damp, omega);       // proven bit pattern
    bool slow;
    if (t == 1) slow = active && slow_t1_from_sim0(sim0);
    else        slow = active && !fast_omega(damp, omega);
    if (active && !slow) out[i] = omega;      // fast path: proven == loop

    unsigned long long mask = __ballot(slow);
    int lane = tid & 63, wid = tid >> 6;
    if (lane == 0) wc[wid] = (unsigned)__popcll(mask);
    __syncthreads();
    if (slow) {
        unsigned pos = 0;
        for (int w = 0; w < wid; ++w) pos += wc[w];
        pos += (unsigned)__popcll(mask & ((1ull << lane) - 1ull));
        sidx[pos]  = (unsigned)i;
        ssim[pos]  = sim0;
        sdamp[pos] = damp;
        somega[pos] = omega;
    }
    __syncthreads();
    if (tid >= 64) return;                    // waves 1-3 free their slots

    unsigned S = wc[0] + wc[1] + wc[2] + wc[3];
    for (unsigned j = (unsigned)tid; j < S; j += 64u) {
        float r = (t == 1) ? loop_t1(ssim[j], sdamp[j], somega[j])
                           : loop_gen(p, ssim[j], sdamp[j], somega[j]);
        out[sidx[j]] = r;
    }
}

extern "C" void kernel_launch(void* const* d_in, const int* in_sizes, int n_in,
                              void* d_out, int out_size, void* d_ws, size_t ws_size,
                              hipStream_t stream) {
    const float* x        = (const float*)d_in[0];
    const int*   osc_type = (const int*)d_in[1];
    float*       out      = (float*)d_out;
    int n = in_sizes[0];
    int NB = (n + 255) / 256;

    k_fused<<<NB, 256, 0, stream>>>(x, osc_type, out, n);
}